// Round 2
// baseline (133.884 us; speedup 1.0000x reference)
//
#include <hip/hip_runtime.h>
#include <hip/hip_bf16.h>

// ContrastiveLoss (SupCon-style), N=4096 rows, K=256 dim, TEMP=0.5.
// loss = mean over same-label off-diag pairs of [log(neg_i + e_ij) - t2_ij].
// e <= e^2 ~ 7.4, neg >= ~550 -> log(neg+e) = log n + e/n (2nd-order dropped,
// <=1e-4 rel [R7]). Stats symmetric (e_ij = e_ji) -> per-COLUMN sums:
// exsum, pexp, pt2, pcnt; neg = exsum - pexp;
// loss = S_j [c log n + pe/n - tt] / S_j c.
//
// R14 == R13 resubmit (R13 bench was an infra flake: "container failed
// twice", no pytest/profile evidence against the kernel).
// R13 theory: counters showed all top-5 dispatches are 40us harness poison
// fills -> each of our kernels <40us; modeled GPU work ~10-15us vs 79us
// measured -> plateau is per-launch overhead + inter-kernel drains. So:
// FUSE K3 into K2. Epilogue: quad-shuffle col sums -> cross-wi LDS
// pre-reduce (512 atomics/block, 512K total, 32/address) into
// colstats[4][4096] -> ticket; block with ticket==1023 runs the closed-form
// finalize (64KB coherent loads, 16 logf/thread, block reduce, out[0]).
// Removes 1 launch + 1 grid drain + the 4MB part[] roundtrip.
//
// pk8 layout per 16-row tile (4096 B):
//   byte[u*1024 + quad*256 + r16*16 + h*8 + j] = fp8(norm8[r16][quad*8+(2u+h)*32+j])
// -> chunk (tile,u) = 1KB = one gll16/dwordx4 row; lane's 16B = c-steps
// {2u,2u+1} (k_local = quad*8 + j).
// C/D: col = lane&15, row = (lane>>4)*4 + reg  [learn_hip m89/m91; R3-R12
// validated end-to-end]. x8 scaling; acc = 64*sim -> t2 = acc * 2^-5 exact.
//
// ws: [0,1MB) pk8; [2MB,+64KB) colstats[4][4096] f32; then acc[4]
//   (acc[2] = ticket as int; rest spare). K1 zeroes colstats+acc in-graph
//   (ws is poisoned between iterations).

#define N_ROWS 4096
#define K_DIM  256

typedef __attribute__((ext_vector_type(4))) float float4v;    // MFMA C/D
typedef __attribute__((ext_vector_type(4))) float f4;
typedef __attribute__((ext_vector_type(4))) int   int4v;
typedef __attribute__((ext_vector_type(2))) long  long2v;     // 2 x 8B frags

#define PK_OFF    0
#define CS_OFF    (2 * 1024 * 1024)               // colstats[4][4096] f32
#define ACC_OFF   (CS_OFF + 4 * N_ROWS * 4)       // acc[4]

// async global->LDS, 16B/lane: dest = wave-uniform base + lane*16 [m97 path]
__device__ __forceinline__ void gll16(const void* g, void* l) {
    __builtin_amdgcn_global_load_lds(
        (const __attribute__((address_space(1))) unsigned int*)g,
        (__attribute__((address_space(3))) unsigned int*)l, 16, 0, 0);
}

// ---------------------------------------------------------------------------
// K1: block = one 16-row tile. Coalesced float4 loads -> LDS, per-row norms
// via 16-lane shuffle groups, x8-scaled fp8 pack, 16B/thread coalesced store.
// Also zeroes this tile's 256B slice of colstats (+acc on tile 0).
__global__ void normalize_kernel(const float* __restrict__ emb,
                                 unsigned char* __restrict__ pk8,
                                 float* __restrict__ colstats,
                                 float* __restrict__ acc) {
    int tile = blockIdx.x, t = threadIdx.x;
    __shared__ float lds[16 * 256];
    __shared__ float sc[16];
    const f4* src = (const f4*)(emb + tile * 16 * 256);
    f4* dst4 = (f4*)lds;
    #pragma unroll
    for (int it = 0; it < 4; ++it) dst4[t + 256 * it] = src[t + 256 * it];
    __syncthreads();
    int wave = t >> 6, lane = t & 63;
    int row = wave * 4 + (lane >> 4);          // 4 rows per wave
    float s = 0.f;
    #pragma unroll
    for (int m = 0; m < 16; ++m) {
        float x = lds[row * 256 + (lane & 15) + 16 * m];
        s += x * x;
    }
    s += __shfl_xor(s, 1); s += __shfl_xor(s, 2);
    s += __shfl_xor(s, 4); s += __shfl_xor(s, 8);
    float scale = 1.0f / fmaxf(sqrtf(s), 1e-12f);
    if ((lane & 15) == 0) sc[row] = scale;
    __syncthreads();
    // pack 16 bytes: fixed (u, quad, r16) per thread; h,j sweep the 16B
    int u = t >> 6, quad = (t >> 4) & 3, r16 = t & 15;
    float s8 = sc[r16] * 8.0f;
    const float* lr = lds + r16 * 256;
    int4v wv;
    #pragma unroll
    for (int wi = 0; wi < 4; ++wi) {           // word wi = bytes 4wi..4wi+3
        int h  = wi >> 1;
        int j0 = (wi & 1) * 4;
        int kb = quad * 8 + (2 * u + h) * 32 + j0;
        float v0 = lr[kb + 0] * s8, v1 = lr[kb + 1] * s8;
        float v2 = lr[kb + 2] * s8, v3 = lr[kb + 3] * s8;
        int wd = __builtin_amdgcn_cvt_pk_fp8_f32(v0, v1, 0, 0);
        wd     = __builtin_amdgcn_cvt_pk_fp8_f32(v2, v3, wd, 1);
        wv[wi] = wd;
    }
    *(int4v*)(pk8 + tile * 4096 + t * 16) = wv;
    // zero colstats: 256 tiles x 16 float4 = 16384 floats
    if (t < 16) ((f4*)colstats)[tile * 16 + t] = (f4){0.f, 0.f, 0.f, 0.f};
    if (tile == 0 && t < 4) acc[t] = 0.0f;     // [2] = ticket
}

// ---------------------------------------------------------------------------
// K2: fp8 fused sim/exp/stats + global reduce + finalize. Grid 1024
// (XCD-swizzled) = 32x32 blocktiles of 128x128; 4 waves in 2x2, each a 64x64
// subtile (4x4 MFMA frags). B-panel (32KB) staged via gll16 (async); A-frags
// loaded straight to VGPRs. ONE barrier, 16 ds_read_b128 + 128 MFMA per wave.
// Epilogue: quad-shuffles give every lane the full 64-row column sum (stat
// selected by quad); wi==0 waves park theirs in LDS, wi==1 waves add and
// issue 4 atomicAdds/lane into colstats. Ticket 1023 block finalizes.
__global__ __launch_bounds__(256, 3)
void negsum_kernel(const unsigned char* __restrict__ pk8,
                   const int* __restrict__ labels,
                   float* __restrict__ colstats,
                   float* __restrict__ acc,
                   float* __restrict__ out) {
    __shared__ __align__(16) unsigned char Bs8[32768];   // 8 tiles x 4 chunks
    __shared__ float red[2][4][64];                      // [wj][stat][col]
    __shared__ int   lastf;
    __shared__ float fin[8];
    int t = threadIdx.x;
    int w = t >> 6, lane = t & 63;
    int lane16 = lane & 15, quad = lane >> 4;
    // XCD swizzle: 4 consecutive bi per XCD (A-panel stays L2-local)
    int xcd = blockIdx.x & 7, local = blockIdx.x >> 3;   // local 0..127
    int bi = xcd * 4 + (local >> 5);                     // 0..31
    int bj = local & 31;
    int wi = w >> 1, wj = w & 1;

    int ibase = bi * 128 + wi * 64;
    int jbase = bj * 128 + wj * 64;
    const char* pkb = (const char*)pk8;        // tile16 = 4KB, chunk = 1KB

    // ---- B-panel: 32 chunks of 1KB via async gll16 (8 per wave) ----
    #pragma unroll
    for (int u = 0; u < 8; ++u) {
        int c8 = w * 8 + u, tl = c8 >> 2, cs = c8 & 3;
        gll16(pkb + (((bj * 8 + tl) << 12) | (cs << 10)) + lane * 16,
              Bs8 + (c8 << 10));
    }
    // ---- A-frags straight to VGPRs (4 it-tiles x 4 cs, 16B each) ----
    long2v av[4][4];
    #pragma unroll
    for (int it = 0; it < 4; ++it)
        #pragma unroll
        for (int cs = 0; cs < 4; ++cs)
            av[it][cs] = *(const long2v*)(pkb
                + (((bi * 8 + wi * 4 + it) << 12) | (cs << 10)) + lane * 16);

    int labi[16], labj[4];
    #pragma unroll
    for (int it = 0; it < 4; ++it)
        #pragma unroll
        for (int r = 0; r < 4; ++r)
            labi[it * 4 + r] = labels[ibase + it * 16 + quad * 4 + r];
    #pragma unroll
    for (int jt = 0; jt < 4; ++jt)
        labj[jt] = labels[jbase + jt * 16 + lane16];

    float4v acc4[4][4];
    #pragma unroll
    for (int a = 0; a < 4; ++a)
        #pragma unroll
        for (int b = 0; b < 4; ++b)
            acc4[a][b] = (float4v){0.f, 0.f, 0.f, 0.f};

    __syncthreads();                           // drains gll16s (and A loads)

    #pragma unroll
    for (int cs = 0; cs < 4; ++cs) {
        long2v bv[4];
        #pragma unroll
        for (int jt = 0; jt < 4; ++jt)
            bv[jt] = *(const long2v*)(Bs8
                     + (((((wj * 4 + jt) << 2) | cs) << 10)) + lane * 16);
        #pragma unroll
        for (int h = 0; h < 2; ++h)
            #pragma unroll
            for (int it = 0; it < 4; ++it)
                #pragma unroll
                for (int jt = 0; jt < 4; ++jt)
                    acc4[it][jt] = __builtin_amdgcn_mfma_f32_16x16x32_fp8_fp8(
                        av[it][cs][h], bv[jt][h], acc4[it][jt], 0, 0, 0);
    }

    // epilogue: per-column stats (== per-row by symmetry); acc = 64*sim
    float ex[4] = {0,0,0,0}, pe[4] = {0,0,0,0};
    float tt[4] = {0,0,0,0}, pc[4] = {0,0,0,0};
    #pragma unroll
    for (int it = 0; it < 4; ++it) {
        #pragma unroll
        for (int jt = 0; jt < 4; ++jt) {
            int j = jbase + jt * 16 + lane16;
            #pragma unroll
            for (int r = 0; r < 4; ++r) {
                int i = ibase + it * 16 + quad * 4 + r;
                float t2 = acc4[it][jt][r] * 0.03125f;  // 2*sim, exact pow2
                float e  = __expf(t2);
                bool keep = (i != j);
                bool same = (labi[it * 4 + r] == labj[jt]);
                ex[jt] += keep ? e : 0.0f;
                float m = (same && keep) ? 1.0f : 0.0f;
                pe[jt] = fmaf(m, e,  pe[jt]);
                tt[jt] = fmaf(m, t2, tt[jt]);
                pc[jt] += m;
            }
        }
    }
    // full 64-row column sums land in ALL lanes; stat index = quad
    float vs[4];
    #pragma unroll
    for (int jt = 0; jt < 4; ++jt) {
        float v0 = ex[jt], v1 = pe[jt], v2 = tt[jt], v3 = pc[jt];
        v0 += __shfl_xor(v0, 16); v0 += __shfl_xor(v0, 32);
        v1 += __shfl_xor(v1, 16); v1 += __shfl_xor(v1, 32);
        v2 += __shfl_xor(v2, 16); v2 += __shfl_xor(v2, 32);
        v3 += __shfl_xor(v3, 16); v3 += __shfl_xor(v3, 32);
        float vsel = (quad == 0) ? v0 : (quad == 1) ? v1
                   : (quad == 2) ? v2 : v3;
        vs[jt] = vsel;
        if (wi == 0) red[wj][quad][jt * 16 + lane16] = vsel;
    }
    __syncthreads();
    if (wi == 1) {                             // 4 atomics/lane, 512/block
        #pragma unroll
        for (int jt = 0; jt < 4; ++jt) {
            int col = jbase + jt * 16 + lane16;
            atomicAdd(colstats + (quad << 12) + col,
                      vs[jt] + red[wj][quad][jt * 16 + lane16]);
        }
    }
    __threadfence();
    __syncthreads();                           // this block's atomics issued+fenced
    if (t == 0) {
        int tk = atomicAdd((int*)(acc + 2), 1);
        lastf = (tk == 1023) ? 1 : 0;
    }
    __syncthreads();
    if (lastf) {                               // all 1023 others have fenced
        float lsum = 0.f, csum = 0.f;
        #pragma unroll
        for (int c = 0; c < 16; ++c) {
            int col = (c << 8) + t;            // coalesced across the wave
            float exs = __hip_atomic_load(colstats + col,
                            __ATOMIC_RELAXED, __HIP_MEMORY_SCOPE_AGENT);
            float pes = __hip_atomic_load(colstats + 4096 + col,
                            __ATOMIC_RELAXED, __HIP_MEMORY_SCOPE_AGENT);
            float tts = __hip_atomic_load(colstats + 2 * 4096 + col,
                            __ATOMIC_RELAXED, __HIP_MEMORY_SCOPE_AGENT);
            float pcs = __hip_atomic_load(colstats + 3 * 4096 + col,
                            __ATOMIC_RELAXED, __HIP_MEMORY_SCOPE_AGENT);
            if (pcs > 0.f) {
                float n = exs - pes;           // neg = exsum - pexp
                lsum += pcs * logf(n) + pes / n - tts;
                csum += pcs;
            }
        }
        #pragma unroll
        for (int m = 1; m < 64; m <<= 1) {
            lsum += __shfl_xor(lsum, m);
            csum += __shfl_xor(csum, m);
        }
        if (lane == 0) { fin[w] = lsum; fin[4 + w] = csum; }
        __syncthreads();
        if (t == 0)
            out[0] = (fin[0] + fin[1] + fin[2] + fin[3]) /
                     (fin[4] + fin[5] + fin[6] + fin[7]);
    }
}

// ---------------------------------------------------------------------------
extern "C" void kernel_launch(void* const* d_in, const int* in_sizes, int n_in,
                              void* d_out, int out_size, void* d_ws, size_t ws_size,
                              hipStream_t stream) {
    const float* emb    = (const float*)d_in[0];
    const int*   labels = (const int*)d_in[1];
    float* out = (float*)d_out;
    char*  ws  = (char*)d_ws;

    unsigned char* pk8      = (unsigned char*)(ws + PK_OFF);
    float*         colstats = (float*)(ws + CS_OFF);
    float*         acc      = (float*)(ws + ACC_OFF);

    normalize_kernel<<<N_ROWS / 16, 256, 0, stream>>>(emb, pk8, colstats, acc);
    negsum_kernel<<<1024, 256, 0, stream>>>(pk8, labels, colstats, acc, out);
}

// Round 3
// 95.295 us; speedup vs baseline: 1.4049x; 1.4049x over previous
//
#include <hip/hip_runtime.h>
#include <hip/hip_bf16.h>

// ContrastiveLoss (SupCon-style), N=4096 rows, K=256 dim, TEMP=0.5.
// loss = mean over same-label off-diag pairs of [log(neg_i + e_ij) - t2_ij].
// e <= e^2 ~ 7.4, neg >= ~550 -> log(neg+e) = log n + e/n (2nd-order dropped,
// <=1e-4 rel [R7]). Stats symmetric (e_ij = e_ji) -> per-COLUMN sums:
// exsum, pexp, pt2, pcnt; neg = exsum - pexp;
// loss = S_j [c log n + pe/n - tt] / S_j c.
//
// R15: R13/R14 fusion POST-MORTEM: fused negsum = 79.5us alone, MfmaUtil
// 3.95% (3.1us real MFMA), ~85% idle -> the 512K device-scope atomics +
// per-block threadfence + 1024 same-address ticket atomics serialize
// (R11's lesson again). REVERTED to R12's 3-kernel no-atomic-data flow.
// New lever: SYMMETRY. sim and all stats are symmetric -> compute only the
// upper triangle of the 32x32 blocktile grid (528 blocks vs 1024).
// Diagonal blocks: col-stats as before. Off-diag blocks: col-stats PLUS
// mirror row-stats (reduce over jt + shfl over lane16), written to part
// slice 2bj+wj at columns i. Every part cell written exactly once (waves
// (wi,wj) x transpose tile the mirror block's cells) -> no atomics.
// ~2x less MFMA + staging; epilogue VALU ~breaks even; 528 blocks fit one
// occupancy round (<=768).
//
// pk8 layout per 16-row tile (4096 B):
//   byte[u*1024 + quad*256 + r16*16 + h*8 + j] = fp8(norm8[r16][quad*8+(2u+h)*32+j])
// -> chunk (tile,u) = 1KB = one gll16/dwordx4 row; lane's 16B = c-steps
// {2u,2u+1} (k_local = quad*8 + j).
// C/D: col = lane&15, row = (lane>>4)*4 + reg  [learn_hip m89/m91; R3-R12
// validated end-to-end]. x8 scaling; acc = 64*sim -> t2 = acc * 2^-5 exact.
//
// ws: [0,1MB) pk8; [2MB,6MB) part[4][64][4096] f32; [6MB,+16B) acc[4]
//   (acc[0]=loss, acc[1]=cnt, acc[2]=ticket, acc[3]=pad).

#define N_ROWS 4096
#define K_DIM  256

typedef __attribute__((ext_vector_type(4))) float float4v;    // MFMA C/D
typedef __attribute__((ext_vector_type(4))) float f4;
typedef __attribute__((ext_vector_type(4))) int   int4v;
typedef __attribute__((ext_vector_type(2))) long  long2v;     // 2 x 8B frags

#define PK_OFF    0
#define PART_OFF  (2 * 1024 * 1024)
#define ACC_OFF   (PART_OFF + 4 * 64 * N_ROWS * 4)     // +4 MB

// async global->LDS, 16B/lane: dest = wave-uniform base + lane*16 [m97 path]
__device__ __forceinline__ void gll16(const void* g, void* l) {
    __builtin_amdgcn_global_load_lds(
        (const __attribute__((address_space(1))) unsigned int*)g,
        (__attribute__((address_space(3))) unsigned int*)l, 16, 0, 0);
}

// ---------------------------------------------------------------------------
// K1: block = one 16-row tile. Coalesced float4 loads -> LDS, per-row norms
// via 16-lane shuffle groups, x8-scaled fp8 pack, 16B/thread coalesced store.
__global__ void normalize_kernel(const float* __restrict__ emb,
                                 unsigned char* __restrict__ pk8,
                                 float* __restrict__ acc) {
    int tile = blockIdx.x, t = threadIdx.x;
    __shared__ float lds[16 * 256];
    __shared__ float sc[16];
    const f4* src = (const f4*)(emb + tile * 16 * 256);
    f4* dst4 = (f4*)lds;
    #pragma unroll
    for (int it = 0; it < 4; ++it) dst4[t + 256 * it] = src[t + 256 * it];
    __syncthreads();
    int wave = t >> 6, lane = t & 63;
    int row = wave * 4 + (lane >> 4);          // 4 rows per wave
    float s = 0.f;
    #pragma unroll
    for (int m = 0; m < 16; ++m) {
        float x = lds[row * 256 + (lane & 15) + 16 * m];
        s += x * x;
    }
    s += __shfl_xor(s, 1); s += __shfl_xor(s, 2);
    s += __shfl_xor(s, 4); s += __shfl_xor(s, 8);
    float scale = 1.0f / fmaxf(sqrtf(s), 1e-12f);
    if ((lane & 15) == 0) sc[row] = scale;
    __syncthreads();
    // pack 16 bytes: fixed (u, quad, r16) per thread; h,j sweep the 16B
    int u = t >> 6, quad = (t >> 4) & 3, r16 = t & 15;
    float s8 = sc[r16] * 8.0f;
    const float* lr = lds + r16 * 256;
    int4v wv;
    #pragma unroll
    for (int wi = 0; wi < 4; ++wi) {           // word wi = bytes 4wi..4wi+3
        int h  = wi >> 1;
        int j0 = (wi & 1) * 4;
        int kb = quad * 8 + (2 * u + h) * 32 + j0;
        float v0 = lr[kb + 0] * s8, v1 = lr[kb + 1] * s8;
        float v2 = lr[kb + 2] * s8, v3 = lr[kb + 3] * s8;
        int wd = __builtin_amdgcn_cvt_pk_fp8_f32(v0, v1, 0, 0);
        wd     = __builtin_amdgcn_cvt_pk_fp8_f32(v2, v3, wd, 1);
        wv[wi] = wd;
    }
    *(int4v*)(pk8 + tile * 4096 + t * 16) = wv;
    if (tile == 0 && t < 4) acc[t] = 0.0f;     // loss, cnt, ticket, pad
}

// ---------------------------------------------------------------------------
// K2: fp8 fused sim/exp/stats, UPPER-TRIANGLE grid of 528 blocks.
// Block (bi<=bj) covers the 128x128 tile; 4 waves in 2x2, each 64x64
// (4x4 MFMA frags). B-panel (32KB) via async gll16; A-frags direct to VGPRs.
// ONE barrier, 16 ds_read_b128 + 128 MFMA per wave.
// Col-stats (all blocks): quad-shuffle reduce -> part[st][2bi+wi][col j].
// Row-stats (bi<bj only): second pass over acc4, per-it reduce over jt +
// shfl over lane16 bits -> part[st][2bj+wj][row i]. Exactly-once coverage.
__global__ __launch_bounds__(256, 3)
void negsum_kernel(const unsigned char* __restrict__ pk8,
                   const int* __restrict__ labels,
                   float* __restrict__ part) {
    __shared__ __align__(16) unsigned char Bs8[32768];   // 8 tiles x 4 chunks
    int t = threadIdx.x;
    int w = t >> 6, lane = t & 63;
    int lane16 = lane & 15, quad = lane >> 4;
    // upper-triangle mapping: b -> (bi, bj), bi <= bj (uniform scalar loop)
    int bi = 0, rem = blockIdx.x;
    while (rem >= 32 - bi) { rem -= 32 - bi; ++bi; }
    int bj = bi + rem;
    int wi = w >> 1, wj = w & 1;

    int ibase = bi * 128 + wi * 64;
    int jbase = bj * 128 + wj * 64;
    const char* pkb = (const char*)pk8;        // tile16 = 4KB, chunk = 1KB

    // ---- B-panel: 32 chunks of 1KB via async gll16 (8 per wave) ----
    #pragma unroll
    for (int u = 0; u < 8; ++u) {
        int c8 = w * 8 + u, tl = c8 >> 2, cs = c8 & 3;
        gll16(pkb + (((bj * 8 + tl) << 12) | (cs << 10)) + lane * 16,
              Bs8 + (c8 << 10));
    }
    // ---- A-frags straight to VGPRs (4 it-tiles x 4 cs, 16B each) ----
    long2v av[4][4];
    #pragma unroll
    for (int it = 0; it < 4; ++it)
        #pragma unroll
        for (int cs = 0; cs < 4; ++cs)
            av[it][cs] = *(const long2v*)(pkb
                + (((bi * 8 + wi * 4 + it) << 12) | (cs << 10)) + lane * 16);

    int labi[16], labj[4];
    #pragma unroll
    for (int it = 0; it < 4; ++it)
        #pragma unroll
        for (int r = 0; r < 4; ++r)
            labi[it * 4 + r] = labels[ibase + it * 16 + quad * 4 + r];
    #pragma unroll
    for (int jt = 0; jt < 4; ++jt)
        labj[jt] = labels[jbase + jt * 16 + lane16];

    float4v acc[4][4];
    #pragma unroll
    for (int a = 0; a < 4; ++a)
        #pragma unroll
        for (int b = 0; b < 4; ++b)
            acc[a][b] = (float4v){0.f, 0.f, 0.f, 0.f};

    __syncthreads();                           // drains gll16s (and A loads)

    #pragma unroll
    for (int cs = 0; cs < 4; ++cs) {
        long2v bv[4];
        #pragma unroll
        for (int jt = 0; jt < 4; ++jt)
            bv[jt] = *(const long2v*)(Bs8
                     + (((((wj * 4 + jt) << 2) | cs) << 10)) + lane * 16);
        #pragma unroll
        for (int h = 0; h < 2; ++h)
            #pragma unroll
            for (int it = 0; it < 4; ++it)
                #pragma unroll
                for (int jt = 0; jt < 4; ++jt)
                    acc[it][jt] = __builtin_amdgcn_mfma_f32_16x16x32_fp8_fp8(
                        av[it][cs][h], bv[jt][h], acc[it][jt], 0, 0, 0);
    }

    // ---- pass 1: per-column stats (chunk 2bi+wi, cols jbase..) ----
    float ex[4] = {0,0,0,0}, pe[4] = {0,0,0,0};
    float tt[4] = {0,0,0,0}, pc[4] = {0,0,0,0};
    #pragma unroll
    for (int it = 0; it < 4; ++it) {
        #pragma unroll
        for (int jt = 0; jt < 4; ++jt) {
            int j = jbase + jt * 16 + lane16;
            #pragma unroll
            for (int r = 0; r < 4; ++r) {
                int i = ibase + it * 16 + quad * 4 + r;
                float t2 = acc[it][jt][r] * 0.03125f;   // 2*sim, exact pow2
                float e  = __expf(t2);
                bool keep = (i != j);                   // only diag blocks hit
                bool same = (labi[it * 4 + r] == labj[jt]);
                ex[jt] += keep ? e : 0.0f;
                float m = (same && keep) ? 1.0f : 0.0f;
                pe[jt] = fmaf(m, e,  pe[jt]);
                tt[jt] = fmaf(m, t2, tt[jt]);
                pc[jt] += m;
            }
        }
    }
    int i64 = bi * 2 + wi;                     // this wave's 64-row chunk
    #pragma unroll
    for (int jt = 0; jt < 4; ++jt) {
        float v0 = ex[jt], v1 = pe[jt], v2 = tt[jt], v3 = pc[jt];
        v0 += __shfl_xor(v0, 16); v0 += __shfl_xor(v0, 32);
        v1 += __shfl_xor(v1, 16); v1 += __shfl_xor(v1, 32);
        v2 += __shfl_xor(v2, 16); v2 += __shfl_xor(v2, 32);
        v3 += __shfl_xor(v3, 16); v3 += __shfl_xor(v3, 32);
        if (quad == 0) {
            int col = jbase + jt * 16 + lane16;
            part[((0 * 64 + i64) << 12) + col] = v0;
            part[((1 * 64 + i64) << 12) + col] = v1;
            part[((2 * 64 + i64) << 12) + col] = v2;
            part[((3 * 64 + i64) << 12) + col] = v3;
        }
    }

    // ---- pass 2 (off-diag only): mirror row stats (chunk 2bj+wj, cols i) ----
    if (bi != bj) {                            // i != j guaranteed
        int j64 = bj * 2 + wj;
        #pragma unroll
        for (int it = 0; it < 4; ++it) {
            float rex[4] = {0,0,0,0}, rpe[4] = {0,0,0,0};
            float rtt[4] = {0,0,0,0}, rpc[4] = {0,0,0,0};
            #pragma unroll
            for (int jt = 0; jt < 4; ++jt) {
                bool same0 = (labi[it * 4 + 0] == labj[jt]);
                bool same1 = (labi[it * 4 + 1] == labj[jt]);
                bool same2 = (labi[it * 4 + 2] == labj[jt]);
                bool same3 = (labi[it * 4 + 3] == labj[jt]);
                #pragma unroll
                for (int r = 0; r < 4; ++r) {
                    float t2 = acc[it][jt][r] * 0.03125f;
                    float e  = __expf(t2);
                    bool same = (r == 0) ? same0 : (r == 1) ? same1
                              : (r == 2) ? same2 : same3;
                    float m = same ? 1.0f : 0.0f;
                    rex[r] += e;
                    rpe[r] = fmaf(m, e,  rpe[r]);
                    rtt[r] = fmaf(m, t2, rtt[r]);
                    rpc[r] += m;
                }
            }
            #pragma unroll
            for (int r = 0; r < 4; ++r) {      // reduce across lane16 bits
                float v0 = rex[r], v1 = rpe[r], v2 = rtt[r], v3 = rpc[r];
                v0 += __shfl_xor(v0, 1); v0 += __shfl_xor(v0, 2);
                v0 += __shfl_xor(v0, 4); v0 += __shfl_xor(v0, 8);
                v1 += __shfl_xor(v1, 1); v1 += __shfl_xor(v1, 2);
                v1 += __shfl_xor(v1, 4); v1 += __shfl_xor(v1, 8);
                v2 += __shfl_xor(v2, 1); v2 += __shfl_xor(v2, 2);
                v2 += __shfl_xor(v2, 4); v2 += __shfl_xor(v2, 8);
                v3 += __shfl_xor(v3, 1); v3 += __shfl_xor(v3, 2);
                v3 += __shfl_xor(v3, 4); v3 += __shfl_xor(v3, 8);
                if (lane16 == 0) {             // 4 lanes (one per quad) store
                    int i = ibase + it * 16 + quad * 4 + r;
                    part[((0 * 64 + j64) << 12) + i] = v0;
                    part[((1 * 64 + j64) << 12) + i] = v1;
                    part[((2 * 64 + j64) << 12) + i] = v2;
                    part[((3 * 64 + j64) << 12) + i] = v3;
                }
            }
        }
    }
}

// ---------------------------------------------------------------------------
// K3: slice-parallel rowreduce. Grid 128 x 256: block = 32 rows; thread
// (rl = t>>3, sl = t&7) sums 8 chunks of row (blk*32+rl); shfl over sl,
// per-row closed form on sl==0 lanes, wave+block reduce, ticket finalize.
__global__ void rowreduce_kernel(const float* __restrict__ part,
                                 float* __restrict__ acc,
                                 float* __restrict__ out) {
    int t = threadIdx.x;
    int rl = t >> 3, sl = t & 7;
    int row = blockIdx.x * 32 + rl;
    float s[4];
    #pragma unroll
    for (int st = 0; st < 4; ++st) {
        float v = 0.f;
        #pragma unroll
        for (int c = 0; c < 8; ++c)
            v += part[((st * 64 + (sl * 8 + c)) << 12) + row];
        s[st] = v;
    }
    #pragma unroll
    for (int st = 0; st < 4; ++st) {           // reduce over the 8 slices
        s[st] += __shfl_xor(s[st], 1);
        s[st] += __shfl_xor(s[st], 2);
        s[st] += __shfl_xor(s[st], 4);
    }
    float lsum = 0.f, pcm = 0.f;
    if (sl == 0 && s[3] > 0.f) {
        float n = s[0] - s[1];                 // neg = exsum - pexp
        lsum = s[3] * logf(n) + s[1] / n - s[2];
        pcm  = s[3];
    }
    #pragma unroll
    for (int m = 1; m < 64; m <<= 1) {         // full-wave sum (masked lanes=0)
        lsum += __shfl_xor(lsum, m);
        pcm  += __shfl_xor(pcm,  m);
    }
    __shared__ float sl4[4], sc4[4];
    int wave = t >> 6, lane = t & 63;
    if (lane == 0) { sl4[wave] = lsum; sc4[wave] = pcm; }
    __syncthreads();
    if (t == 0) {
        atomicAdd(&acc[0], sl4[0] + sl4[1] + sl4[2] + sl4[3]);
        atomicAdd(&acc[1], sc4[0] + sc4[1] + sc4[2] + sc4[3]);
        __threadfence();
        int ticket = atomicAdd((int*)(acc + 2), 1);
        if (ticket == 127) {
            float ls = atomicAdd(&acc[0], 0.0f);
            float cs = atomicAdd(&acc[1], 0.0f);
            out[0] = ls / cs;
        }
    }
}

// ---------------------------------------------------------------------------
extern "C" void kernel_launch(void* const* d_in, const int* in_sizes, int n_in,
                              void* d_out, int out_size, void* d_ws, size_t ws_size,
                              hipStream_t stream) {
    const float* emb    = (const float*)d_in[0];
    const int*   labels = (const int*)d_in[1];
    float* out = (float*)d_out;
    char*  ws  = (char*)d_ws;

    unsigned char* pk8  = (unsigned char*)(ws + PK_OFF);
    float*         part = (float*)(ws + PART_OFF);
    float*         acc  = (float*)(ws + ACC_OFF);

    normalize_kernel<<<N_ROWS / 16, 256, 0, stream>>>(emb, pk8, acc);
    negsum_kernel<<<528, 256, 0, stream>>>(pk8, labels, part);
    rowreduce_kernel<<<128, 256, 0, stream>>>(part, acc, out);
}

// Round 4
// 78.516 us; speedup vs baseline: 1.7052x; 1.2137x over previous
//
#include <hip/hip_runtime.h>
#include <hip/hip_bf16.h>

// ContrastiveLoss (SupCon-style), N=4096 rows, K=256 dim, TEMP=0.5.
// loss = mean over same-label off-diag pairs of [log(neg_i + e_ij) - t2_ij].
// e <= e^2 ~ 7.4, neg >= ~550 -> log(neg+e) = log n + e/n (2nd-order dropped,
// <=1e-4 rel [R7]). Stats symmetric (e_ij = e_ji) -> per-COLUMN sums:
// exsum, pexp, pt2, pcnt; neg = exsum - pexp;
// loss = S_j [c log n + pe/n - tt] / S_j c.
//
// R16: REVERT to R12-known-good K1/K2 (79.3us, stable across 2 containers).
// Post-mortems: R13/R14 fusion (512K colstats atomics + fences) = +54us;
// R15 symmetry (mirror pass-2 epilogue, no XCD swizzle) = +16us. Both were
// epilogue/coherence ADDITIONS to K2; both regressed far beyond the cycle
// model. K2 additions are high-risk -> this round only SUBTRACTS:
// K3 lane remap for coalescing: old (rl=t>>3, sl=t&7) gave adjacent lanes
// 16KB-apart slices (8 x 32B segments per wave load). New (rl=t&31, sl=t>>5)
// gives 2 x 128B contiguous segments; cross-slice reduce = shfl_xor(32) +
// 4x4x32 LDS pass. Ticket tail unchanged (128 atomics, known-good).
//
// pk8 layout per 16-row tile (4096 B):
//   byte[u*1024 + quad*256 + r16*16 + h*8 + j] = fp8(norm8[r16][quad*8+(2u+h)*32+j])
// -> chunk (tile,u) = 1KB = one gll16/dwordx4 row; lane's 16B = c-steps
// {2u,2u+1} (k_local = quad*8 + j).
// C/D: col = lane&15, row = (lane>>4)*4 + reg  [learn_hip m89/m91; R3-R12
// validated end-to-end]. x8 scaling; acc = 64*sim -> t2 = acc * 2^-5 exact.
//
// ws: [0,1MB) pk8; [2MB,6MB) part[4][64][4096] f32; [6MB,+16B) acc[4]
//   (acc[0]=loss, acc[1]=cnt, acc[2]=ticket, acc[3]=pad).

#define N_ROWS 4096
#define K_DIM  256

typedef __attribute__((ext_vector_type(4))) float float4v;    // MFMA C/D
typedef __attribute__((ext_vector_type(4))) float f4;
typedef __attribute__((ext_vector_type(4))) int   int4v;
typedef __attribute__((ext_vector_type(2))) long  long2v;     // 2 x 8B frags

#define PK_OFF    0
#define PART_OFF  (2 * 1024 * 1024)
#define ACC_OFF   (PART_OFF + 4 * 64 * N_ROWS * 4)     // +4 MB

// async global->LDS, 16B/lane: dest = wave-uniform base + lane*16 [m97 path]
__device__ __forceinline__ void gll16(const void* g, void* l) {
    __builtin_amdgcn_global_load_lds(
        (const __attribute__((address_space(1))) unsigned int*)g,
        (__attribute__((address_space(3))) unsigned int*)l, 16, 0, 0);
}

// ---------------------------------------------------------------------------
// K1: block = one 16-row tile. Coalesced float4 loads -> LDS, per-row norms
// via 16-lane shuffle groups, x8-scaled fp8 pack, 16B/thread coalesced store.
__global__ void normalize_kernel(const float* __restrict__ emb,
                                 unsigned char* __restrict__ pk8,
                                 float* __restrict__ acc) {
    int tile = blockIdx.x, t = threadIdx.x;
    __shared__ float lds[16 * 256];
    __shared__ float sc[16];
    const f4* src = (const f4*)(emb + tile * 16 * 256);
    f4* dst4 = (f4*)lds;
    #pragma unroll
    for (int it = 0; it < 4; ++it) dst4[t + 256 * it] = src[t + 256 * it];
    __syncthreads();
    int wave = t >> 6, lane = t & 63;
    int row = wave * 4 + (lane >> 4);          // 4 rows per wave
    float s = 0.f;
    #pragma unroll
    for (int m = 0; m < 16; ++m) {
        float x = lds[row * 256 + (lane & 15) + 16 * m];
        s += x * x;
    }
    s += __shfl_xor(s, 1); s += __shfl_xor(s, 2);
    s += __shfl_xor(s, 4); s += __shfl_xor(s, 8);
    float scale = 1.0f / fmaxf(sqrtf(s), 1e-12f);
    if ((lane & 15) == 0) sc[row] = scale;
    __syncthreads();
    // pack 16 bytes: fixed (u, quad, r16) per thread; h,j sweep the 16B
    int u = t >> 6, quad = (t >> 4) & 3, r16 = t & 15;
    float s8 = sc[r16] * 8.0f;
    const float* lr = lds + r16 * 256;
    int4v wv;
    #pragma unroll
    for (int wi = 0; wi < 4; ++wi) {           // word wi = bytes 4wi..4wi+3
        int h  = wi >> 1;
        int j0 = (wi & 1) * 4;
        int kb = quad * 8 + (2 * u + h) * 32 + j0;
        float v0 = lr[kb + 0] * s8, v1 = lr[kb + 1] * s8;
        float v2 = lr[kb + 2] * s8, v3 = lr[kb + 3] * s8;
        int wd = __builtin_amdgcn_cvt_pk_fp8_f32(v0, v1, 0, 0);
        wd     = __builtin_amdgcn_cvt_pk_fp8_f32(v2, v3, wd, 1);
        wv[wi] = wd;
    }
    *(int4v*)(pk8 + tile * 4096 + t * 16) = wv;
    if (tile == 0 && t < 4) acc[t] = 0.0f;     // loss, cnt, ticket, pad
}

// ---------------------------------------------------------------------------
// K2: fp8 fused sim/exp/stats. Grid 1024 (XCD-swizzled) = 32x32 blocktiles of
// 128x128; 4 waves in 2x2, each a 64x64 subtile (4x4 MFMA frags).
// B-panel (32KB) staged via gll16 (async); A-frags loaded straight to VGPRs
// (16 dwordx4/wave, in flight alongside the gll16s). ONE barrier, then
// 16 ds_read_b128 + 128 MFMA per wave. 32KB LDS -> 3 blocks/CU.
__global__ __launch_bounds__(256, 3)
void negsum_kernel(const unsigned char* __restrict__ pk8,
                   const int* __restrict__ labels,
                   float* __restrict__ part) {
    __shared__ __align__(16) unsigned char Bs8[32768];   // 8 tiles x 4 chunks
    int t = threadIdx.x;
    int w = t >> 6, lane = t & 63;
    int lane16 = lane & 15, quad = lane >> 4;
    // XCD swizzle: 4 consecutive bi per XCD (A-panel stays L2-local)
    int xcd = blockIdx.x & 7, local = blockIdx.x >> 3;   // local 0..127
    int bi = xcd * 4 + (local >> 5);                     // 0..31
    int bj = local & 31;
    int wi = w >> 1, wj = w & 1;

    int ibase = bi * 128 + wi * 64;
    int jbase = bj * 128 + wj * 64;
    const char* pkb = (const char*)pk8;        // tile16 = 4KB, chunk = 1KB

    // ---- B-panel: 32 chunks of 1KB via async gll16 (8 per wave) ----
    #pragma unroll
    for (int u = 0; u < 8; ++u) {
        int c8 = w * 8 + u, tl = c8 >> 2, cs = c8 & 3;
        gll16(pkb + (((bj * 8 + tl) << 12) | (cs << 10)) + lane * 16,
              Bs8 + (c8 << 10));
    }
    // ---- A-frags straight to VGPRs (4 it-tiles x 4 cs, 16B each) ----
    long2v av[4][4];
    #pragma unroll
    for (int it = 0; it < 4; ++it)
        #pragma unroll
        for (int cs = 0; cs < 4; ++cs)
            av[it][cs] = *(const long2v*)(pkb
                + (((bi * 8 + wi * 4 + it) << 12) | (cs << 10)) + lane * 16);

    int labi[16], labj[4];
    #pragma unroll
    for (int it = 0; it < 4; ++it)
        #pragma unroll
        for (int r = 0; r < 4; ++r)
            labi[it * 4 + r] = labels[ibase + it * 16 + quad * 4 + r];
    #pragma unroll
    for (int jt = 0; jt < 4; ++jt)
        labj[jt] = labels[jbase + jt * 16 + lane16];

    float4v acc[4][4];
    #pragma unroll
    for (int a = 0; a < 4; ++a)
        #pragma unroll
        for (int b = 0; b < 4; ++b)
            acc[a][b] = (float4v){0.f, 0.f, 0.f, 0.f};

    __syncthreads();                           // drains gll16s (and A loads)

    #pragma unroll
    for (int cs = 0; cs < 4; ++cs) {
        long2v bv[4];
        #pragma unroll
        for (int jt = 0; jt < 4; ++jt)
            bv[jt] = *(const long2v*)(Bs8
                     + (((((wj * 4 + jt) << 2) | cs) << 10)) + lane * 16);
        #pragma unroll
        for (int h = 0; h < 2; ++h)
            #pragma unroll
            for (int it = 0; it < 4; ++it)
                #pragma unroll
                for (int jt = 0; jt < 4; ++jt)
                    acc[it][jt] = __builtin_amdgcn_mfma_f32_16x16x32_fp8_fp8(
                        av[it][cs][h], bv[jt][h], acc[it][jt], 0, 0, 0);
    }

    // epilogue: per-column stats (== per-row by symmetry); acc = 64*sim
    float ex[4] = {0,0,0,0}, pe[4] = {0,0,0,0};
    float tt[4] = {0,0,0,0}, pc[4] = {0,0,0,0};
    #pragma unroll
    for (int it = 0; it < 4; ++it) {
        #pragma unroll
        for (int jt = 0; jt < 4; ++jt) {
            int j = jbase + jt * 16 + lane16;
            #pragma unroll
            for (int r = 0; r < 4; ++r) {
                int i = ibase + it * 16 + quad * 4 + r;
                float t2 = acc[it][jt][r] * 0.03125f;   // 2*sim, exact pow2
                float e  = __expf(t2);
                bool keep = (i != j);
                bool same = (labi[it * 4 + r] == labj[jt]);
                ex[jt] += keep ? e : 0.0f;
                float m = (same && keep) ? 1.0f : 0.0f;
                pe[jt] = fmaf(m, e,  pe[jt]);
                tt[jt] = fmaf(m, t2, tt[jt]);
                pc[jt] += m;
            }
        }
    }
    int i64 = bi * 2 + wi;                     // this wave's 64-row chunk
    #pragma unroll
    for (int jt = 0; jt < 4; ++jt) {
        float v0 = ex[jt], v1 = pe[jt], v2 = tt[jt], v3 = pc[jt];
        v0 += __shfl_xor(v0, 16); v0 += __shfl_xor(v0, 32);
        v1 += __shfl_xor(v1, 16); v1 += __shfl_xor(v1, 32);
        v2 += __shfl_xor(v2, 16); v2 += __shfl_xor(v2, 32);
        v3 += __shfl_xor(v3, 16); v3 += __shfl_xor(v3, 32);
        if (quad == 0) {
            int col = jbase + jt * 16 + lane16;
            part[((0 * 64 + i64) << 12) + col] = v0;
            part[((1 * 64 + i64) << 12) + col] = v1;
            part[((2 * 64 + i64) << 12) + col] = v2;
            part[((3 * 64 + i64) << 12) + col] = v3;
        }
    }
}

// ---------------------------------------------------------------------------
// K3: slice-parallel rowreduce, coalesced mapping. Grid 128 x 256:
// block = 32 rows; thread (rl = t&31, sl = t>>5) sums 8 chunks of row
// (blk*32+rl) in slice sl -> each wave-load = 2 x 128B contiguous segments
// (was 8 x 32B with the old rl=t>>3 map). Cross-slice reduce: shfl_xor(32)
// pairs slices within a wave, then a 4x4x32 LDS pass across waves.
// Closed form on t<32, 32-lane shfl reduce, ticket finalize (unchanged).
__global__ void rowreduce_kernel(const float* __restrict__ part,
                                 float* __restrict__ acc,
                                 float* __restrict__ out) {
    int t = threadIdx.x;
    int rl = t & 31, sl = t >> 5;              // 8 slices x 32 rows
    int row = blockIdx.x * 32 + rl;
    float s[4];
    #pragma unroll
    for (int st = 0; st < 4; ++st) {
        float v = 0.f;
        #pragma unroll
        for (int c = 0; c < 8; ++c)
            v += part[((st * 64 + (sl * 8 + c)) << 12) + row];
        s[st] = v;
    }
    // combine the wave's two slices (lane ^ 32 = same row, other slice)
    #pragma unroll
    for (int st = 0; st < 4; ++st) s[st] += __shfl_xor(s[st], 32);
    __shared__ float sred[4][4][32];           // [wave][stat][row]
    int wave = t >> 6, lane = t & 63;
    if (lane < 32) {
        #pragma unroll
        for (int st = 0; st < 4; ++st) sred[wave][st][lane] = s[st];
    }
    __syncthreads();
    float lsum = 0.f, pcm = 0.f;
    if (t < 32) {
        float tot[4];
        #pragma unroll
        for (int st = 0; st < 4; ++st)
            tot[st] = sred[0][st][t] + sred[1][st][t]
                    + sred[2][st][t] + sred[3][st][t];
        if (tot[3] > 0.f) {
            float n = tot[0] - tot[1];         // neg = exsum - pexp
            lsum = tot[3] * logf(n) + tot[1] / n - tot[2];
            pcm  = tot[3];
        }
    }
    #pragma unroll
    for (int m = 1; m < 32; m <<= 1) {         // lanes 0..31 of wave 0
        lsum += __shfl_xor(lsum, m);
        pcm  += __shfl_xor(pcm,  m);
    }
    if (t == 0) {
        atomicAdd(&acc[0], lsum);
        atomicAdd(&acc[1], pcm);
        __threadfence();
        int ticket = atomicAdd((int*)(acc + 2), 1);
        if (ticket == 127) {
            float ls = atomicAdd(&acc[0], 0.0f);
            float cs = atomicAdd(&acc[1], 0.0f);
            out[0] = ls / cs;
        }
    }
}

// ---------------------------------------------------------------------------
extern "C" void kernel_launch(void* const* d_in, const int* in_sizes, int n_in,
                              void* d_out, int out_size, void* d_ws, size_t ws_size,
                              hipStream_t stream) {
    const float* emb    = (const float*)d_in[0];
    const int*   labels = (const int*)d_in[1];
    float* out = (float*)d_out;
    char*  ws  = (char*)d_ws;

    unsigned char* pk8  = (unsigned char*)(ws + PK_OFF);
    float*         part = (float*)(ws + PART_OFF);
    float*         acc  = (float*)(ws + ACC_OFF);

    normalize_kernel<<<N_ROWS / 16, 256, 0, stream>>>(emb, pk8, acc);
    negsum_kernel<<<1024, 256, 0, stream>>>(pk8, labels, part);
    rowreduce_kernel<<<128, 256, 0, stream>>>(part, acc, out);
}